// Round 1
// baseline (870.964 us; speedup 1.0000x reference)
//
#include <hip/hip_runtime.h>
#include <hip/hip_bf16.h>

// out[b,o] = sum_k x[b,k] * W[o,k] + bias[o]
// x: (1048576, 128) fp32, W: (128, 128) fp32 row-major (o,k), b: (128,1) fp32
// Strategy: bf16 MFMA (16x16x32), W staged in LDS (bf16, padded rows),
// x A-fragments loaded straight from global fp32 and converted in-register.
// Memory-bound: 1.07 GB total HBM traffic -> ~170 us floor at 6.3 TB/s.

typedef __attribute__((ext_vector_type(8))) short bf16x8;   // 8 bf16 = 4 VGPRs
typedef __attribute__((ext_vector_type(4))) float f32x4;    // MFMA C/D

#define LDSW 136   // 128 + 8 bf16 pad: row stride 272B -> 2-way bank aliasing (free)

__device__ __forceinline__ short f2bf(float f) {
    union { __hip_bfloat16 h; short s; } u;
    u.h = __float2bfloat16(f);
    return u.s;
}

__global__ __launch_bounds__(256, 2)
void linear_mfma_kernel(const float* __restrict__ x,
                        const float* __restrict__ W,
                        const float* __restrict__ bias,
                        float* __restrict__ out)
{
    __shared__ short sW[128 * LDSW];   // bf16 bits, row-major (n, k), padded

    const int tid  = threadIdx.x;
    const int lane = tid & 63;
    const int wave = tid >> 6;
    const int lr   = lane & 15;   // A row-in-tile / B col / C col
    const int lq   = lane >> 4;   // quad index

    // ---- Stage W (128x128 fp32) -> LDS bf16. 4096 float4 chunks / 256 thr = 16 each.
    #pragma unroll
    for (int it = 0; it < 16; ++it) {
        const int i  = tid + it * 256;     // float4 index
        const int n  = i >> 5;             // 32 float4 per 128-elem row
        const int k4 = (i & 31) << 2;
        const float4 w = ((const float4*)W)[i];
        short4 p;
        p.x = f2bf(w.x); p.y = f2bf(w.y); p.z = f2bf(w.z); p.w = f2bf(w.w);
        *(short4*)&sW[n * LDSW + k4] = p;  // 8B-aligned (272*n + 2*k4)
    }

    // ---- Per-wave output: 32 rows x 128 cols (2 m-tiles x 8 n-tiles of 16x16)
    const long row0 = (long)blockIdx.x * 128 + wave * 32;

    // bias per n-tile (L2-resident broadcast-ish loads)
    float bv[8];
    #pragma unroll
    for (int nt = 0; nt < 8; ++nt) bv[nt] = bias[nt * 16 + lr];

    // ---- A fragments direct from global (fp32 -> bf16 in-register).
    // A layout: A[m = lane&15][k = lq*8 + j], 8 consecutive k per lane.
    bf16x8 afrag[2][4];
    #pragma unroll
    for (int mt = 0; mt < 2; ++mt) {
        const float* xr = x + (row0 + mt * 16 + lr) * 128 + lq * 8;
        #pragma unroll
        for (int ks = 0; ks < 4; ++ks) {
            const float4 f0 = *(const float4*)(xr + ks * 32);
            const float4 f1 = *(const float4*)(xr + ks * 32 + 4);
            bf16x8 a;
            a[0] = f2bf(f0.x); a[1] = f2bf(f0.y); a[2] = f2bf(f0.z); a[3] = f2bf(f0.w);
            a[4] = f2bf(f1.x); a[5] = f2bf(f1.y); a[6] = f2bf(f1.z); a[7] = f2bf(f1.w);
            afrag[mt][ks] = a;
        }
    }

    __syncthreads();   // sW ready

    f32x4 acc[2][8];
    #pragma unroll
    for (int mt = 0; mt < 2; ++mt)
        #pragma unroll
        for (int nt = 0; nt < 8; ++nt)
            acc[mt][nt] = (f32x4){0.f, 0.f, 0.f, 0.f};

    // ---- MFMA main loop: B frag = W[n = nt*16+lr][k = ks*32 + lq*8 ..+8] from LDS
    #pragma unroll
    for (int ks = 0; ks < 4; ++ks) {
        #pragma unroll
        for (int nt = 0; nt < 8; ++nt) {
            const bf16x8 bfrag =
                *(const bf16x8*)&sW[(nt * 16 + lr) * LDSW + ks * 32 + lq * 8];
            acc[0][nt] = __builtin_amdgcn_mfma_f32_16x16x32_bf16(
                afrag[0][ks], bfrag, acc[0][nt], 0, 0, 0);
            acc[1][nt] = __builtin_amdgcn_mfma_f32_16x16x32_bf16(
                afrag[1][ks], bfrag, acc[1][nt], 0, 0, 0);
        }
    }

    // ---- Epilogue: C/D layout col = lane&15, row = lq*4 + reg  [m89/m91 verified]
    #pragma unroll
    for (int mt = 0; mt < 2; ++mt) {
        #pragma unroll
        for (int r = 0; r < 4; ++r) {
            float* orow = out + (row0 + mt * 16 + lq * 4 + r) * 128 + lr;
            #pragma unroll
            for (int nt = 0; nt < 8; ++nt)
                orow[nt * 16] = acc[mt][nt][r] + bv[nt];
        }
    }
}

extern "C" void kernel_launch(void* const* d_in, const int* in_sizes, int n_in,
                              void* d_out, int out_size, void* d_ws, size_t ws_size,
                              hipStream_t stream) {
    const float* x = (const float*)d_in[0];   // (1048576, 128)
    const float* W = (const float*)d_in[1];   // (128, 128)
    const float* b = (const float*)d_in[2];   // (128, 1)
    float* out = (float*)d_out;               // (1048576, 128)

    const int BATCH = 1048576;
    dim3 grid(BATCH / 128);   // 8192 blocks, each does a 128x128 output tile
    dim3 block(256);
    linear_mfma_kernel<<<grid, block, 0, stream>>>(x, W, b, out);
}